// Round 1
// baseline (12581.054 us; speedup 1.0000x reference)
//
#include <hip/hip_runtime.h>

// LSTM persistent-RNN kernel for MI355X (gfx950).
// B=64, T=512, D=1024, H=1024. out[t][b][h] fp32.
//
// Phase A (cvt_x_kernel): x fp32 -> bf16 (ws), ~30us, memory-bound.
// Phase B (lstm_persist): 128 blocks x 256 thr, weights in VGPRs as bf16 MFMA
// fragments (loaded once), 512 steps with a device-scope arrive/wait barrier.
// Each block owns 8 hidden units (32 gate columns). K=2048 split 4 ways
// across waves; cross-wave reduce via LDS; c-state in registers.

typedef short short8 __attribute__((ext_vector_type(8)));
typedef float f32x4 __attribute__((ext_vector_type(4)));

#define NBLK 128
#define TPB 256

__device__ __forceinline__ unsigned bfbits(float f) {
  unsigned u = __float_as_uint(f);
  return ((u + 0x7fffu + ((u >> 16) & 1u)) >> 16) & 0xffffu;  // RNE
}

__device__ __forceinline__ short8 cvt8(const float* p) {
  const float4* q = (const float4*)p;
  float4 a = q[0], b = q[1];
  short8 r;
  r[0] = (short)bfbits(a.x); r[1] = (short)bfbits(a.y);
  r[2] = (short)bfbits(a.z); r[3] = (short)bfbits(a.w);
  r[4] = (short)bfbits(b.x); r[5] = (short)bfbits(b.y);
  r[6] = (short)bfbits(b.z); r[7] = (short)bfbits(b.w);
  return r;
}

__device__ __forceinline__ float sigmoidf_(float x) {
  return 1.0f / (1.0f + __expf(-x));
}
__device__ __forceinline__ float tanhf_(float x) {
  float ax = fabsf(x);
  float e = __expf(-2.0f * ax);          // in (0,1], never overflows
  float r = (1.0f - e) / (1.0f + e);
  return copysignf(r, x);
}

__global__ void cvt_x_kernel(const float* __restrict__ x,
                             unsigned short* __restrict__ xb, int n4) {
  int i = blockIdx.x * blockDim.x + threadIdx.x;
  int stride = gridDim.x * blockDim.x;
  const float4* xv = (const float4*)x;
  uint2* ov = (uint2*)xb;
  for (; i < n4; i += stride) {
    float4 v = xv[i];
    uint2 o;
    o.x = bfbits(v.x) | (bfbits(v.y) << 16);
    o.y = bfbits(v.z) | (bfbits(v.w) << 16);
    ov[i] = o;
  }
}

// Gate order: 0=i, 1=f, 2=o, 3=c(g). Block bid owns hidden units
// [bid*8, bid*8+8). Its 32 gate-columns: col c = 8*g + u.
// MFMA 16x16x32 bf16. A-frag: lane l -> row l&15, k = 8*(l>>4)+j.
// B-frag: lane l -> col l&15, k = 8*(l>>4)+j. C/D: col=l&15,
// row=(l>>4)*4+reg (HW-verified per guide m89/m91).
__global__ __launch_bounds__(TPB, 1) void lstm_persist(
    const float* __restrict__ x, const unsigned short* __restrict__ xb,
    const float* __restrict__ Wi, const float* __restrict__ Wf,
    const float* __restrict__ Wo, const float* __restrict__ Wc,
    const float* __restrict__ bi, const float* __restrict__ bfv,
    const float* __restrict__ bo, const float* __restrict__ bc,
    unsigned short* __restrict__ hbuf, unsigned* __restrict__ cnt,
    float* __restrict__ out) {
  constexpr int B = 64, T = 512, D = 1024, H = 1024;
  const int tid = threadIdx.x;
  const int bid = blockIdx.x;
  const int lane = tid & 63;
  const int w = tid >> 6;        // wave 0..3 -> K-slice [256w, 256w+256)
  const int cl = lane & 15;
  const int kg = lane >> 4;      // k-group within fragment
  const int j0 = bid * 8;

  __shared__ float part[4][32][68];  // [wave][col][row+pad] fp32 partials

  // ---- Load weight fragments into registers (once) ----
  const float* Wg[4] = {Wi, Wf, Wo, Wc};
  short8 bxw[2][8], bhw[2][8];
#pragma unroll
  for (int nt = 0; nt < 2; ++nt) {
    int g = 2 * nt + (cl >> 3);
    const float* wrow = Wg[g] + (size_t)(j0 + (cl & 7)) * 2048;
#pragma unroll
    for (int kf = 0; kf < 8; ++kf) {
      int kx = 256 * w + 32 * kf + 8 * kg;
      bxw[nt][kf] = cvt8(wrow + kx);          // x-part columns [0,1024)
      bhw[nt][kf] = cvt8(wrow + 1024 + kx);   // h-part columns [1024,2048)
    }
  }

  // ---- Activation-stage assignment ----
  const int u = tid & 7;          // hidden unit within block
  const int r0 = 2 * (tid >> 3);  // 2 batch rows per thread
  float biasv[4] = {bi[j0 + u], bfv[j0 + u], bo[j0 + u], bc[j0 + u]};
  float cst[2] = {0.0f, 0.0f};    // cell state (registers, persistent)

  // ---- Zero h_{-1} (hbuf[1]) cooperatively, then global arrive ----
  unsigned* hz = (unsigned*)(hbuf + 64 * 1024);
  hz[bid * TPB + tid] = 0u;       // 128*256 uints == 64*1024 bf16
  __threadfence();
  __syncthreads();
  if (tid == 0)
    __hip_atomic_fetch_add(cnt, 1u, __ATOMIC_RELEASE, __HIP_MEMORY_SCOPE_AGENT);

  const int kxbase = 256 * w + 8 * kg;

  for (int t = 0; t < T; ++t) {
    const unsigned short* hprev = hbuf + (((t & 1) ^ 1) * 65536);
    unsigned short* hnext = hbuf + ((t & 1) * 65536);

    f32x4 acc[4][2];
#pragma unroll
    for (int mt = 0; mt < 4; ++mt)
#pragma unroll
      for (int nt = 0; nt < 2; ++nt) acc[mt][nt] = (f32x4)0.0f;

    // ---- x-part MFMAs (independent of h -> issued before barrier wait) ----
#pragma unroll
    for (int kf = 0; kf < 8; ++kf) {
      int kx = kxbase + 32 * kf;
      short8 af[4];
      if (xb) {
#pragma unroll
        for (int mt = 0; mt < 4; ++mt) {
          int b = 16 * mt + cl;
          af[mt] = *(const short8*)(xb + ((size_t)b * T + t) * D + kx);
        }
      } else {
#pragma unroll
        for (int mt = 0; mt < 4; ++mt) {
          int b = 16 * mt + cl;
          af[mt] = cvt8(x + ((size_t)b * T + t) * D + kx);
        }
      }
#pragma unroll
      for (int mt = 0; mt < 4; ++mt) {
        acc[mt][0] = __builtin_amdgcn_mfma_f32_16x16x32_bf16(af[mt], bxw[0][kf],
                                                             acc[mt][0], 0, 0, 0);
        acc[mt][1] = __builtin_amdgcn_mfma_f32_16x16x32_bf16(af[mt], bxw[1][kf],
                                                             acc[mt][1], 0, 0, 0);
      }
    }

    // ---- Wait for all blocks to have published h_{t-1} ----
    const unsigned target = (unsigned)NBLK * (unsigned)(t + 1);
    if (tid == 0) {
      while (__hip_atomic_load(cnt, __ATOMIC_ACQUIRE, __HIP_MEMORY_SCOPE_AGENT) <
             target)
        __builtin_amdgcn_s_sleep(2);
    }
    __syncthreads();

    // ---- h-part MFMAs ----
#pragma unroll
    for (int kf = 0; kf < 8; ++kf) {
      int kh = kxbase + 32 * kf;
      short8 af[4];
#pragma unroll
      for (int mt = 0; mt < 4; ++mt)
        af[mt] = *(const short8*)(hprev + (16 * mt + cl) * H + kh);
#pragma unroll
      for (int mt = 0; mt < 4; ++mt) {
        acc[mt][0] = __builtin_amdgcn_mfma_f32_16x16x32_bf16(af[mt], bhw[0][kf],
                                                             acc[mt][0], 0, 0, 0);
        acc[mt][1] = __builtin_amdgcn_mfma_f32_16x16x32_bf16(af[mt], bhw[1][kf],
                                                             acc[mt][1], 0, 0, 0);
      }
    }

    // ---- Cross-wave reduce via LDS ----
#pragma unroll
    for (int mt = 0; mt < 4; ++mt)
#pragma unroll
      for (int nt = 0; nt < 2; ++nt)
        *(f32x4*)&part[w][16 * nt + cl][16 * mt + 4 * kg] = acc[mt][nt];
    __syncthreads();

    // ---- Activations + cell update (each thread: unit u, rows r0, r0+1) ----
#pragma unroll
    for (int rr = 0; rr < 2; ++rr) {
      int row = r0 + rr;
      float pre[4];
#pragma unroll
      for (int g = 0; g < 4; ++g) {
        float s = biasv[g];
#pragma unroll
        for (int ww = 0; ww < 4; ++ww) s += part[ww][8 * g + u][row];
        pre[g] = s;
      }
      float iv = sigmoidf_(pre[0]);
      float fv = sigmoidf_(pre[1]);
      float ov = sigmoidf_(pre[2]);
      float gv = tanhf_(pre[3]);
      cst[rr] = fv * cst[rr] + iv * gv;
      float hv = ov * tanhf_(cst[rr]);
      hnext[row * H + j0 + u] = (unsigned short)bfbits(hv);
      out[((size_t)t * B + row) * H + j0 + u] = hv;
    }

    // ---- Publish h_t: fence + arrive ----
    __threadfence();
    __syncthreads();
    if (tid == 0)
      __hip_atomic_fetch_add(cnt, 1u, __ATOMIC_RELEASE,
                             __HIP_MEMORY_SCOPE_AGENT);
  }
}

extern "C" void kernel_launch(void* const* d_in, const int* in_sizes, int n_in,
                              void* d_out, int out_size, void* d_ws,
                              size_t ws_size, hipStream_t stream) {
  const float* x = (const float*)d_in[0];
  const float* Wi = (const float*)d_in[1];
  const float* bi = (const float*)d_in[2];
  const float* Wf = (const float*)d_in[3];
  const float* bfv = (const float*)d_in[4];
  const float* Wo = (const float*)d_in[5];
  const float* bo = (const float*)d_in[6];
  const float* Wc = (const float*)d_in[7];
  const float* bc = (const float*)d_in[8];
  float* out = (float*)d_out;

  char* ws = (char*)d_ws;
  const size_t xb_bytes = (size_t)64 * 512 * 1024 * 2;  // 64 MiB bf16 x
  const size_t small_bytes = (size_t)2 * 64 * 1024 * 2 + 256;  // hbuf + cnt
  unsigned short* xb = nullptr;
  size_t off = 0;
  if (ws_size >= xb_bytes + small_bytes) {
    xb = (unsigned short*)ws;
    off = xb_bytes;
  }
  unsigned short* hbuf = (unsigned short*)(ws + off);
  off += (size_t)2 * 64 * 1024 * 2;
  unsigned* cnt = (unsigned*)(ws + off);

  hipMemsetAsync(cnt, 0, sizeof(unsigned), stream);
  if (xb) cvt_x_kernel<<<2048, 256, 0, stream>>>(x, xb, (64 * 512 * 1024) / 4);
  lstm_persist<<<NBLK, TPB, 0, stream>>>(x, xb, Wi, Wf, Wo, Wc, bi, bfv, bo, bc,
                                         hbuf, cnt, out);
}

// Round 2
// 4798.546 us; speedup vs baseline: 2.6218x; 2.6218x over previous
//
#include <hip/hip_runtime.h>

// LSTM persistent-RNN kernel for MI355X (gfx950).
// B=64, T=512, D=1024, H=1024. out[t][b][h] fp32.
//
// Round 2: remove all compiler cache-maintenance (buffer_wbl2 / buffer_inv)
// from the recurrent loop. h + barrier counter use device-coherent accesses
// (sc0 sc1 / relaxed agent atomics); x and weights stay normally cached.

typedef short short8 __attribute__((ext_vector_type(8)));
typedef float f32x4 __attribute__((ext_vector_type(4)));

#define NBLK 128
#define TPB 256

__device__ __forceinline__ unsigned bfbits(float f) {
  unsigned u = __float_as_uint(f);
  return ((u + 0x7fffu + ((u >> 16) & 1u)) >> 16) & 0xffffu;  // RNE
}

__device__ __forceinline__ short8 cvt8(const float* p) {
  const float4* q = (const float4*)p;
  float4 a = q[0], b = q[1];
  short8 r;
  r[0] = (short)bfbits(a.x); r[1] = (short)bfbits(a.y);
  r[2] = (short)bfbits(a.z); r[3] = (short)bfbits(a.w);
  r[4] = (short)bfbits(b.x); r[5] = (short)bfbits(b.y);
  r[6] = (short)bfbits(b.z); r[7] = (short)bfbits(b.w);
  return r;
}

// Device-coherent 16B load: bypass L1+L2, read from LLC. NOTE: data is NOT
// valid until a following s_waitcnt vmcnt(0) (+ sched_barrier) executes.
__device__ __forceinline__ short8 llc_load16(const unsigned short* p) {
  short8 r;
  asm volatile("global_load_dwordx4 %0, %1, off sc0 sc1"
               : "=v"(r)
               : "v"(p));
  return r;
}

__device__ __forceinline__ float sigmoidf_(float x) {
  return 1.0f / (1.0f + __expf(-x));
}
__device__ __forceinline__ float tanhf_(float x) {
  float ax = fabsf(x);
  float e = __expf(-2.0f * ax);  // in (0,1], never overflows
  float r = (1.0f - e) / (1.0f + e);
  return copysignf(r, x);
}

__global__ void cvt_x_kernel(const float* __restrict__ x,
                             unsigned short* __restrict__ xb, int n4) {
  int i = blockIdx.x * blockDim.x + threadIdx.x;
  int stride = gridDim.x * blockDim.x;
  const float4* xv = (const float4*)x;
  uint2* ov = (uint2*)xb;
  for (; i < n4; i += stride) {
    float4 v = xv[i];
    uint2 o;
    o.x = bfbits(v.x) | (bfbits(v.y) << 16);
    o.y = bfbits(v.z) | (bfbits(v.w) << 16);
    ov[i] = o;
  }
}

// Gate order: 0=i, 1=f, 2=o, 3=c(g). Block bid owns hidden units
// [bid*8, bid*8+8). Its 32 gate-columns: col c = 8*g + u.
// MFMA 16x16x32 bf16. A-frag: lane l -> row l&15, k = 8*(l>>4)+j.
// B-frag: lane l -> col l&15, k = 8*(l>>4)+j. C/D: col=l&15,
// row=(l>>4)*4+reg (HW-verified per guide m89/m91).
__global__ __launch_bounds__(TPB, 1) void lstm_persist(
    const float* __restrict__ x, const unsigned short* __restrict__ xb,
    const float* __restrict__ Wi, const float* __restrict__ Wf,
    const float* __restrict__ Wo, const float* __restrict__ Wc,
    const float* __restrict__ bi, const float* __restrict__ bfv,
    const float* __restrict__ bo, const float* __restrict__ bc,
    unsigned short* __restrict__ hbuf, unsigned* __restrict__ cnt,
    float* __restrict__ out) {
  constexpr int B = 64, T = 512, D = 1024, H = 1024;
  const int tid = threadIdx.x;
  const int bid = blockIdx.x;
  const int lane = tid & 63;
  const int w = tid >> 6;   // wave 0..3 -> K-slice [256w, 256w+256)
  const int cl = lane & 15;
  const int kg = lane >> 4; // k-group within fragment
  const int j0 = bid * 8;

  __shared__ float part[4][32][68];  // [wave][col][row+pad] fp32 partials

  // ---- Load weight fragments into registers (once) ----
  const float* Wg[4] = {Wi, Wf, Wo, Wc};
  short8 bxw[2][8], bhw[2][8];
#pragma unroll
  for (int nt = 0; nt < 2; ++nt) {
    int g = 2 * nt + (cl >> 3);
    const float* wrow = Wg[g] + (size_t)(j0 + (cl & 7)) * 2048;
#pragma unroll
    for (int kf = 0; kf < 8; ++kf) {
      int kx = 256 * w + 32 * kf + 8 * kg;
      bxw[nt][kf] = cvt8(wrow + kx);         // x-part columns [0,1024)
      bhw[nt][kf] = cvt8(wrow + 1024 + kx);  // h-part columns [1024,2048)
    }
  }

  // ---- Activation-stage assignment: thread -> (row, unit-pair) ----
  const int row = tid >> 2;      // batch row 0..63
  const int up = tid & 3;        // unit pair: units 2*up, 2*up+1
  float biasv[4][2];
#pragma unroll
  for (int k = 0; k < 2; ++k) {
    biasv[0][k] = bi[j0 + 2 * up + k];
    biasv[1][k] = bfv[j0 + 2 * up + k];
    biasv[2][k] = bo[j0 + 2 * up + k];
    biasv[3][k] = bc[j0 + 2 * up + k];
  }
  float cst[2] = {0.0f, 0.0f};  // cell state (registers, persistent)

  // ---- Zero h_{-1} (hbuf slot 1) with coherent stores, then arrive ----
  unsigned* hz = (unsigned*)(hbuf + 65536);
  __hip_atomic_store(&hz[bid * TPB + tid], 0u, __ATOMIC_RELAXED,
                     __HIP_MEMORY_SCOPE_AGENT);
  __syncthreads();  // implicit vmcnt(0) drains the coherent stores
  if (tid == 0)
    __hip_atomic_fetch_add(cnt, 1u, __ATOMIC_RELAXED, __HIP_MEMORY_SCOPE_AGENT);

  const int kxbase = 256 * w + 8 * kg;

  for (int t = 0; t < T; ++t) {
    const unsigned short* hprev = hbuf + (((t & 1) ^ 1) * 65536);
    unsigned short* hnext = hbuf + ((t & 1) * 65536);

    f32x4 acc[4][2];
#pragma unroll
    for (int mt = 0; mt < 4; ++mt)
#pragma unroll
      for (int nt = 0; nt < 2; ++nt) acc[mt][nt] = (f32x4)0.0f;

    // ---- x-part MFMAs (independent of h -> before the barrier wait) ----
#pragma unroll
    for (int kf = 0; kf < 8; ++kf) {
      int kx = kxbase + 32 * kf;
      short8 af[4];
      if (xb) {
#pragma unroll
        for (int mt = 0; mt < 4; ++mt) {
          int b = 16 * mt + cl;
          af[mt] = *(const short8*)(xb + ((size_t)b * T + t) * D + kx);
        }
      } else {
#pragma unroll
        for (int mt = 0; mt < 4; ++mt) {
          int b = 16 * mt + cl;
          af[mt] = cvt8(x + ((size_t)b * T + t) * D + kx);
        }
      }
#pragma unroll
      for (int mt = 0; mt < 4; ++mt) {
        acc[mt][0] = __builtin_amdgcn_mfma_f32_16x16x32_bf16(
            af[mt], bxw[0][kf], acc[mt][0], 0, 0, 0);
        acc[mt][1] = __builtin_amdgcn_mfma_f32_16x16x32_bf16(
            af[mt], bxw[1][kf], acc[mt][1], 0, 0, 0);
      }
    }

    // ---- Wait for all blocks to have published h_{t-1} (relaxed poll) ----
    const unsigned target = (unsigned)NBLK * (unsigned)(t + 1);
    if (tid == 0) {
      while (__hip_atomic_load(cnt, __ATOMIC_RELAXED,
                               __HIP_MEMORY_SCOPE_AGENT) < target)
        __builtin_amdgcn_s_sleep(1);
    }
    __syncthreads();
    asm volatile("" ::: "memory");  // no h-loads hoisted above the poll

    // ---- Issue ALL h-fragment loads (coherent, 32 in flight) ----
    short8 ah[8][4];
#pragma unroll
    for (int kf = 0; kf < 8; ++kf) {
      int kh = kxbase + 32 * kf;
#pragma unroll
      for (int mt = 0; mt < 4; ++mt)
        ah[kf][mt] = llc_load16(hprev + (16 * mt + cl) * H + kh);
    }
    asm volatile("s_waitcnt vmcnt(0)" ::: "memory");
    __builtin_amdgcn_sched_barrier(0);  // rule #18: no MFMA hoisted above wait

    // ---- h-part MFMAs ----
#pragma unroll
    for (int kf = 0; kf < 8; ++kf) {
#pragma unroll
      for (int mt = 0; mt < 4; ++mt) {
        acc[mt][0] = __builtin_amdgcn_mfma_f32_16x16x32_bf16(
            ah[kf][mt], bhw[0][kf], acc[mt][0], 0, 0, 0);
        acc[mt][1] = __builtin_amdgcn_mfma_f32_16x16x32_bf16(
            ah[kf][mt], bhw[1][kf], acc[mt][1], 0, 0, 0);
      }
    }

    // ---- Cross-wave reduce via LDS ----
#pragma unroll
    for (int mt = 0; mt < 4; ++mt)
#pragma unroll
      for (int nt = 0; nt < 2; ++nt)
        *(f32x4*)&part[w][16 * nt + cl][16 * mt + 4 * kg] = acc[mt][nt];
    __syncthreads();

    // ---- Activations + cell update: thread -> (row, units 2up..2up+1) ----
    float hv[2];
#pragma unroll
    for (int k = 0; k < 2; ++k) {
      int u = 2 * up + k;
      float pre[4];
#pragma unroll
      for (int g = 0; g < 4; ++g) {
        float s = biasv[g][k];
#pragma unroll
        for (int ww = 0; ww < 4; ++ww) s += part[ww][8 * g + u][row];
        pre[g] = s;
      }
      float iv = sigmoidf_(pre[0]);
      float fv = sigmoidf_(pre[1]);
      float ov = sigmoidf_(pre[2]);
      float gv = tanhf_(pre[3]);
      cst[k] = fv * cst[k] + iv * gv;
      hv[k] = ov * tanhf_(cst[k]);
    }
    // packed coherent h store (1 dword), normal out store (2 fp32)
    unsigned hpack = bfbits(hv[0]) | (bfbits(hv[1]) << 16);
    __hip_atomic_store((unsigned*)(hnext + row * H + j0 + 2 * up), hpack,
                       __ATOMIC_RELAXED, __HIP_MEMORY_SCOPE_AGENT);
    float2 o2 = make_float2(hv[0], hv[1]);
    *(float2*)(out + ((size_t)t * B + row) * H + j0 + 2 * up) = o2;

    // ---- Publish h_t: syncthreads (implicit vmcnt(0) drain) + arrive ----
    __syncthreads();
    asm volatile("" ::: "memory");
    if (tid == 0)
      __hip_atomic_fetch_add(cnt, 1u, __ATOMIC_RELAXED,
                             __HIP_MEMORY_SCOPE_AGENT);
  }
}

extern "C" void kernel_launch(void* const* d_in, const int* in_sizes, int n_in,
                              void* d_out, int out_size, void* d_ws,
                              size_t ws_size, hipStream_t stream) {
  const float* x = (const float*)d_in[0];
  const float* Wi = (const float*)d_in[1];
  const float* bi = (const float*)d_in[2];
  const float* Wf = (const float*)d_in[3];
  const float* bfv = (const float*)d_in[4];
  const float* Wo = (const float*)d_in[5];
  const float* bo = (const float*)d_in[6];
  const float* Wc = (const float*)d_in[7];
  const float* bc = (const float*)d_in[8];
  float* out = (float*)d_out;

  char* ws = (char*)d_ws;
  const size_t xb_bytes = (size_t)64 * 512 * 1024 * 2;         // 64 MiB bf16 x
  const size_t small_bytes = (size_t)2 * 64 * 1024 * 2 + 256;  // hbuf + cnt
  unsigned short* xb = nullptr;
  size_t off = 0;
  if (ws_size >= xb_bytes + small_bytes) {
    xb = (unsigned short*)ws;
    off = xb_bytes;
  }
  unsigned short* hbuf = (unsigned short*)(ws + off);
  off += (size_t)2 * 64 * 1024 * 2;
  unsigned* cnt = (unsigned*)(ws + off);

  hipMemsetAsync(cnt, 0, sizeof(unsigned), stream);
  if (xb) cvt_x_kernel<<<2048, 256, 0, stream>>>(x, xb, (64 * 512 * 1024) / 4);
  lstm_persist<<<NBLK, TPB, 0, stream>>>(x, xb, Wi, Wf, Wo, Wc, bi, bfv, bo, bc,
                                         hbuf, cnt, out);
}

// Round 3
// 4450.217 us; speedup vs baseline: 2.8271x; 1.0783x over previous
//
#include <hip/hip_runtime.h>

// LSTM persistent-RNN kernel for MI355X (gfx950).
// B=64, T=512, D=1024, H=1024. out[t][b][h] fp32.
//
// Round 3: flag-array barrier (no atomic RMWs; wave-parallel poll),
// out-store moved off the critical path (after arrive, non-temporal),
// h-loads via SGPR-base + imm-offset asm with counted vmcnt waits
// interleaved with the h-MFMAs.

typedef short short8 __attribute__((ext_vector_type(8)));
typedef float f32x4 __attribute__((ext_vector_type(4)));

#define NBLK 128
#define TPB 256

__device__ __forceinline__ unsigned bfbits(float f) {
  unsigned u = __float_as_uint(f);
  return ((u + 0x7fffu + ((u >> 16) & 1u)) >> 16) & 0xffffu;  // RNE
}

__device__ __forceinline__ short8 cvt8(const float* p) {
  const float4* q = (const float4*)p;
  float4 a = q[0], b = q[1];
  short8 r;
  r[0] = (short)bfbits(a.x); r[1] = (short)bfbits(a.y);
  r[2] = (short)bfbits(a.z); r[3] = (short)bfbits(a.w);
  r[4] = (short)bfbits(b.x); r[5] = (short)bfbits(b.y);
  r[6] = (short)bfbits(b.z); r[7] = (short)bfbits(b.w);
  return r;
}

// Device-coherent 16B load from SGPR base + VGPR offset + imm offset.
// Bypasses L1/L2 (sc0 sc1) -> reads LLC-fresh data. NOT valid until a
// following s_waitcnt vmcnt(..) + sched_barrier executes.
template <int OFF>
__device__ __forceinline__ short8 llc_load16s(const unsigned short* base,
                                              int voff) {
  short8 r;
  asm volatile("global_load_dwordx4 %0, %1, %2 offset:%3 sc0 sc1"
               : "=v"(r)
               : "v"(voff), "s"(base), "n"(OFF));
  return r;
}

__device__ __forceinline__ float sigmoidf_(float x) {
  return 1.0f / (1.0f + __expf(-x));
}
__device__ __forceinline__ float tanhf_(float x) {
  float ax = fabsf(x);
  float e = __expf(-2.0f * ax);  // in (0,1], never overflows
  float r = (1.0f - e) / (1.0f + e);
  return copysignf(r, x);
}

__global__ void cvt_x_kernel(const float* __restrict__ x,
                             unsigned short* __restrict__ xb, int n4) {
  int i = blockIdx.x * blockDim.x + threadIdx.x;
  int stride = gridDim.x * blockDim.x;
  const float4* xv = (const float4*)x;
  uint2* ov = (uint2*)xb;
  for (; i < n4; i += stride) {
    float4 v = xv[i];
    uint2 o;
    o.x = bfbits(v.x) | (bfbits(v.y) << 16);
    o.y = bfbits(v.z) | (bfbits(v.w) << 16);
    ov[i] = o;
  }
}

// Gate order: 0=i, 1=f, 2=o, 3=c(g). Block bid owns hidden units
// [bid*8, bid*8+8). Its 32 gate-columns: col c = 8*g + u.
// MFMA 16x16x32 bf16. A-frag: lane l -> row l&15, k = 8*(l>>4)+j.
// B-frag: lane l -> col l&15, k = 8*(l>>4)+j. C/D: col=l&15,
// row=(l>>4)*4+reg (HW-verified per guide m89/m91).
__global__ __launch_bounds__(TPB, 1) void lstm_persist(
    const float* __restrict__ x, const unsigned short* __restrict__ xb,
    const float* __restrict__ Wi, const float* __restrict__ Wf,
    const float* __restrict__ Wo, const float* __restrict__ Wc,
    const float* __restrict__ bi, const float* __restrict__ bfv,
    const float* __restrict__ bo, const float* __restrict__ bc,
    unsigned short* __restrict__ hbuf, unsigned* __restrict__ flags,
    float* __restrict__ out) {
  constexpr int B = 64, T = 512, D = 1024, H = 1024;
  const int tid = threadIdx.x;
  const int bid = blockIdx.x;
  const int lane = tid & 63;
  const int w = tid >> 6;    // wave 0..3 -> K-slice [256w, 256w+256)
  const int cl = lane & 15;
  const int kg = lane >> 4;  // k-group within fragment
  const int j0 = bid * 8;

  __shared__ float part[4][32][68];  // [wave][col][row+pad] fp32 partials

  // ---- Load weight fragments into registers (once) ----
  const float* Wg[4] = {Wi, Wf, Wo, Wc};
  short8 bxw[2][8], bhw[2][8];
#pragma unroll
  for (int nt = 0; nt < 2; ++nt) {
    int g = 2 * nt + (cl >> 3);
    const float* wrow = Wg[g] + (size_t)(j0 + (cl & 7)) * 2048;
#pragma unroll
    for (int kf = 0; kf < 8; ++kf) {
      int kx = 256 * w + 32 * kf + 8 * kg;
      bxw[nt][kf] = cvt8(wrow + kx);         // x-part columns [0,1024)
      bhw[nt][kf] = cvt8(wrow + 1024 + kx);  // h-part columns [1024,2048)
    }
  }

  // ---- Activation-stage assignment: thread -> (row, unit-pair) ----
  const int row = tid >> 2;  // batch row 0..63
  const int up = tid & 3;    // unit pair: units 2*up, 2*up+1
  float biasv[4][2];
#pragma unroll
  for (int k = 0; k < 2; ++k) {
    biasv[0][k] = bi[j0 + 2 * up + k];
    biasv[1][k] = bfv[j0 + 2 * up + k];
    biasv[2][k] = bo[j0 + 2 * up + k];
    biasv[3][k] = bc[j0 + 2 * up + k];
  }
  float cst[2] = {0.0f, 0.0f};  // cell state (registers, persistent)

  const int kxbase = 256 * w + 8 * kg;
  // Per-mt h-load voffsets (bytes), constant across steps:
  int voff[4];
#pragma unroll
  for (int mt = 0; mt < 4; ++mt)
    voff[mt] = (((16 * mt + cl) << 10) + kxbase) * 2;

  // ---- Zero h_{-1} (hbuf slot 1) with coherent stores, then arrive ----
  unsigned* hz = (unsigned*)(hbuf + 65536);
  __hip_atomic_store(&hz[bid * TPB + tid], 0u, __ATOMIC_RELAXED,
                     __HIP_MEMORY_SCOPE_AGENT);
  __syncthreads();  // drains the coherent stores (vmcnt(0) before barrier)
  if (tid == 0)
    __hip_atomic_store(&flags[bid * 32], 1u, __ATOMIC_RELAXED,
                       __HIP_MEMORY_SCOPE_AGENT);

  for (int t = 0; t < T; ++t) {
    const unsigned short* hprev = hbuf + (((t & 1) ^ 1) * 65536);
    unsigned short* hnext = hbuf + ((t & 1) * 65536);

    f32x4 acc[4][2];
#pragma unroll
    for (int mt = 0; mt < 4; ++mt)
#pragma unroll
      for (int nt = 0; nt < 2; ++nt) acc[mt][nt] = (f32x4)0.0f;

    // ---- x-part MFMAs (independent of h -> before the barrier wait) ----
#pragma unroll
    for (int kf = 0; kf < 8; ++kf) {
      int kx = kxbase + 32 * kf;
      short8 af[4];
      if (xb) {
#pragma unroll
        for (int mt = 0; mt < 4; ++mt) {
          int b = 16 * mt + cl;
          af[mt] = *(const short8*)(xb + ((size_t)b * T + t) * D + kx);
        }
      } else {
#pragma unroll
        for (int mt = 0; mt < 4; ++mt) {
          int b = 16 * mt + cl;
          af[mt] = cvt8(x + ((size_t)b * T + t) * D + kx);
        }
      }
#pragma unroll
      for (int mt = 0; mt < 4; ++mt) {
        acc[mt][0] = __builtin_amdgcn_mfma_f32_16x16x32_bf16(
            af[mt], bxw[0][kf], acc[mt][0], 0, 0, 0);
        acc[mt][1] = __builtin_amdgcn_mfma_f32_16x16x32_bf16(
            af[mt], bxw[1][kf], acc[mt][1], 0, 0, 0);
      }
    }

    // ---- Wait: all 128 per-block flags >= t+1 (wave 0, parallel poll) ----
    const unsigned target = (unsigned)(t + 1);
    if (w == 0) {
      const unsigned* f0 = flags + (2 * lane) * 32;
      const unsigned* f1 = flags + (2 * lane + 1) * 32;
      while (true) {
        unsigned a = __hip_atomic_load(f0, __ATOMIC_RELAXED,
                                       __HIP_MEMORY_SCOPE_AGENT);
        unsigned b = __hip_atomic_load(f1, __ATOMIC_RELAXED,
                                       __HIP_MEMORY_SCOPE_AGENT);
        if (__all(a >= target && b >= target)) break;
        __builtin_amdgcn_s_sleep(1);
      }
    }
    __syncthreads();  // also drains vmcnt -> counted waits below are exact
    asm volatile("" ::: "memory");

    // ---- Issue ALL 32 h-fragment loads (coherent, SGPR base + imm) ----
    short8 ah[8][4];
#define HLOAD(kf)                                         \
  ah[kf][0] = llc_load16s<64 * (kf)>(hprev, voff[0]);     \
  ah[kf][1] = llc_load16s<64 * (kf)>(hprev, voff[1]);     \
  ah[kf][2] = llc_load16s<64 * (kf)>(hprev, voff[2]);     \
  ah[kf][3] = llc_load16s<64 * (kf)>(hprev, voff[3]);
    HLOAD(0) HLOAD(1) HLOAD(2) HLOAD(3)
    HLOAD(4) HLOAD(5) HLOAD(6) HLOAD(7)
#undef HLOAD

    // ---- h-part MFMAs, counted-wait interleaved (rule #18 fencing) ----
#define HMFMA(kf, rem)                                                      \
  asm volatile("s_waitcnt vmcnt(" #rem ")" ::: "memory");                   \
  __builtin_amdgcn_sched_barrier(0);                                        \
  {                                                                         \
    _Pragma("unroll") for (int mt = 0; mt < 4; ++mt) {                      \
      acc[mt][0] = __builtin_amdgcn_mfma_f32_16x16x32_bf16(                 \
          ah[kf][mt], bhw[0][kf], acc[mt][0], 0, 0, 0);                     \
      acc[mt][1] = __builtin_amdgcn_mfma_f32_16x16x32_bf16(                 \
          ah[kf][mt], bhw[1][kf], acc[mt][1], 0, 0, 0);                     \
    }                                                                       \
  }
    HMFMA(0, 28) HMFMA(1, 24) HMFMA(2, 20) HMFMA(3, 16)
    HMFMA(4, 12) HMFMA(5, 8) HMFMA(6, 4) HMFMA(7, 0)
#undef HMFMA

    // ---- Cross-wave reduce via LDS ----
#pragma unroll
    for (int mt = 0; mt < 4; ++mt)
#pragma unroll
      for (int nt = 0; nt < 2; ++nt)
        *(f32x4*)&part[w][16 * nt + cl][16 * mt + 4 * kg] = acc[mt][nt];
    __syncthreads();

    // ---- Activations + cell update: thread -> (row, units 2up..2up+1) ----
    float hv[2];
#pragma unroll
    for (int k = 0; k < 2; ++k) {
      int u = 2 * up + k;
      float pre[4];
#pragma unroll
      for (int g = 0; g < 4; ++g) {
        float s = biasv[g][k];
#pragma unroll
        for (int ww = 0; ww < 4; ++ww) s += part[ww][8 * g + u][row];
        pre[g] = s;
      }
      float iv = sigmoidf_(pre[0]);
      float fv = sigmoidf_(pre[1]);
      float ov = sigmoidf_(pre[2]);
      float gv = tanhf_(pre[3]);
      cst[k] = fv * cst[k] + iv * gv;
      hv[k] = ov * tanhf_(cst[k]);
    }
    // packed coherent h store (1 dword) -- the only store that must drain
    unsigned hpack = bfbits(hv[0]) | (bfbits(hv[1]) << 16);
    __hip_atomic_store((unsigned*)(hnext + row * H + j0 + 2 * up), hpack,
                       __ATOMIC_RELAXED, __HIP_MEMORY_SCOPE_AGENT);

    // ---- Publish h_t: drain h stores, then arrive (plain flag store) ----
    __syncthreads();
    asm volatile("" ::: "memory");
    if (tid == 0)
      __hip_atomic_store(&flags[bid * 32], (unsigned)(t + 2), __ATOMIC_RELAXED,
                         __HIP_MEMORY_SCOPE_AGENT);

    // ---- out store AFTER arrive: drains during next step's poll ----
    float* op = out + ((size_t)t * B + row) * H + j0 + 2 * up;
    __builtin_nontemporal_store(hv[0], op);
    __builtin_nontemporal_store(hv[1], op + 1);
  }
}

extern "C" void kernel_launch(void* const* d_in, const int* in_sizes, int n_in,
                              void* d_out, int out_size, void* d_ws,
                              size_t ws_size, hipStream_t stream) {
  const float* x = (const float*)d_in[0];
  const float* Wi = (const float*)d_in[1];
  const float* bi = (const float*)d_in[2];
  const float* Wf = (const float*)d_in[3];
  const float* bfv = (const float*)d_in[4];
  const float* Wo = (const float*)d_in[5];
  const float* bo = (const float*)d_in[6];
  const float* Wc = (const float*)d_in[7];
  const float* bc = (const float*)d_in[8];
  float* out = (float*)d_out;

  char* ws = (char*)d_ws;
  const size_t xb_bytes = (size_t)64 * 512 * 1024 * 2;  // 64 MiB bf16 x
  const size_t hb_bytes = (size_t)2 * 64 * 1024 * 2;    // ping-pong h
  const size_t fl_bytes = (size_t)NBLK * 32 * 4;        // flag array
  unsigned short* xb = nullptr;
  size_t off = 0;
  if (ws_size >= xb_bytes + hb_bytes + fl_bytes) {
    xb = (unsigned short*)ws;
    off = xb_bytes;
  }
  unsigned short* hbuf = (unsigned short*)(ws + off);
  off += hb_bytes;
  unsigned* flags = (unsigned*)(ws + off);

  hipMemsetAsync(flags, 0, fl_bytes, stream);
  if (xb) cvt_x_kernel<<<2048, 256, 0, stream>>>(x, xb, (64 * 512 * 1024) / 4);
  lstm_persist<<<NBLK, TPB, 0, stream>>>(x, xb, Wi, Wf, Wo, Wc, bi, bfv, bo, bc,
                                         hbuf, flags, out);
}